// Round 1
// baseline (3747.965 us; speedup 1.0000x reference)
//
#include <hip/hip_runtime.h>

#define IN_F 128
#define OUT_F 16
#define N_HEADS 4
#define OUT_C 64   // OUT_F * N_HEADS
#define ALPHA 0.2f

// ---- order-preserving float<->uint encoding for atomicMax on floats ----
__device__ __forceinline__ unsigned int enc_f(float f) {
  unsigned int u = __float_as_uint(f);
  return (u & 0x80000000u) ? ~u : (u | 0x80000000u);
}
__device__ __forceinline__ float dec_f(unsigned int u) {
  unsigned int b = (u & 0x80000000u) ? (u & 0x7FFFFFFFu) : ~u;
  return __uint_as_float(b);
}

__global__ __launch_bounds__(64) void k_init(unsigned int* gmax, float* gsum) {
  int t = threadIdx.x;
  if (t < N_HEADS) { gmax[t] = enc_f(-3.0e38f); gsum[t] = 0.f; }
}

// ---- GEMM: Wh = h @ W, plus per-node attention scores s_src, s_dst ----
// block: 256 threads = 64 rows x 4 heads; stages 64 h-rows + full W in LDS.
__global__ __launch_bounds__(256) void k_gemm(
    const float* __restrict__ h, const float* __restrict__ W,
    const float* __restrict__ a_src, const float* __restrict__ a_dst,
    float* __restrict__ Wh, float* __restrict__ ssrc, float* __restrict__ sdst,
    int n_nodes)
{
  __shared__ __align__(16) float Wl[IN_F * OUT_C];   // 32 KB, row-major [k][c]
  __shared__ __align__(16) float hl[64 * 132];       // 33.8 KB, pad 128->132 (bank spread)
  __shared__ float al[2][OUT_C];
  const int t = threadIdx.x;
  const int row0 = blockIdx.x * 64;

  for (int i = t; i < IN_F * OUT_C / 4; i += 256)
    ((float4*)Wl)[i] = ((const float4*)W)[i];
  if (t < OUT_C) { al[0][t] = a_src[t]; al[1][t] = a_dst[t]; }
  for (int i = t; i < 64 * IN_F / 4; i += 256) {
    int r = i >> 5;            // 32 float4 per row
    int c4 = i & 31;
    int gr = row0 + r;
    float4 v = (gr < n_nodes) ? ((const float4*)(h + (size_t)gr * IN_F))[c4]
                              : make_float4(0.f, 0.f, 0.f, 0.f);
    *(float4*)&hl[r * 132 + c4 * 4] = v;
  }
  __syncthreads();

  const int r = t >> 2, head = t & 3;
  const int row = row0 + r;
  if (row >= n_nodes) return;

  float acc[16];
#pragma unroll
  for (int f = 0; f < 16; ++f) acc[f] = 0.f;
  const float* wcol = Wl + head * 16;
  const float* hr = hl + r * 132;
#pragma unroll 4
  for (int k = 0; k < IN_F; ++k) {
    float hv = hr[k];
#pragma unroll
    for (int q = 0; q < 4; ++q) {
      float4 w = *(const float4*)(wcol + k * OUT_C + q * 4);
      acc[q * 4 + 0] += hv * w.x;
      acc[q * 4 + 1] += hv * w.y;
      acc[q * 4 + 2] += hv * w.z;
      acc[q * 4 + 3] += hv * w.w;
    }
  }
  float s0 = 0.f, s1 = 0.f;
#pragma unroll
  for (int f = 0; f < 16; ++f) {
    s0 += acc[f] * al[0][head * 16 + f];
    s1 += acc[f] * al[1][head * 16 + f];
  }
  float* o = Wh + (size_t)row * OUT_C + head * 16;
#pragma unroll
  for (int q = 0; q < 4; ++q)
    ((float4*)o)[q] = make_float4(acc[q * 4], acc[q * 4 + 1], acc[q * 4 + 2], acc[q * 4 + 3]);
  ssrc[row * N_HEADS + head] = s0;
  sdst[row * N_HEADS + head] = s1;
}

// ---- per-head global max over edges ----
__global__ __launch_bounds__(256) void k_emax(
    const int* __restrict__ ei, const float4* __restrict__ ssrc,
    const float4* __restrict__ sdst, unsigned int* __restrict__ gmax, int n_edges)
{
  float m[4] = {-3.0e38f, -3.0e38f, -3.0e38f, -3.0e38f};
  int stride = gridDim.x * blockDim.x;
  for (int e = blockIdx.x * blockDim.x + threadIdx.x; e < n_edges; e += stride) {
    int s = ei[e], d = ei[n_edges + e];
    float4 a = ssrc[s], b = sdst[d];
    float e0 = a.x + b.x; e0 = e0 > 0.f ? e0 : ALPHA * e0;
    float e1 = a.y + b.y; e1 = e1 > 0.f ? e1 : ALPHA * e1;
    float e2 = a.z + b.z; e2 = e2 > 0.f ? e2 : ALPHA * e2;
    float e3 = a.w + b.w; e3 = e3 > 0.f ? e3 : ALPHA * e3;
    m[0] = fmaxf(m[0], e0); m[1] = fmaxf(m[1], e1);
    m[2] = fmaxf(m[2], e2); m[3] = fmaxf(m[3], e3);
  }
  __shared__ float red[4][4];
  int lane = threadIdx.x & 63, wv = threadIdx.x >> 6;
#pragma unroll
  for (int c = 0; c < 4; ++c)
#pragma unroll
    for (int o = 32; o; o >>= 1) m[c] = fmaxf(m[c], __shfl_down(m[c], o));
  if (lane == 0) { red[wv][0] = m[0]; red[wv][1] = m[1]; red[wv][2] = m[2]; red[wv][3] = m[3]; }
  __syncthreads();
  if (threadIdx.x < 4) {
    float v = fmaxf(fmaxf(red[0][threadIdx.x], red[1][threadIdx.x]),
                    fmaxf(red[2][threadIdx.x], red[3][threadIdx.x]));
    atomicMax(gmax + threadIdx.x, enc_f(v));
  }
}

// ---- per-head sum of exp(e - max) ----
__global__ __launch_bounds__(256) void k_esum(
    const int* __restrict__ ei, const float4* __restrict__ ssrc,
    const float4* __restrict__ sdst, const unsigned int* __restrict__ gmax,
    float* __restrict__ gsum, int n_edges)
{
  float M[4];
#pragma unroll
  for (int c = 0; c < 4; ++c) M[c] = dec_f(gmax[c]);
  float acc[4] = {0.f, 0.f, 0.f, 0.f};
  int stride = gridDim.x * blockDim.x;
  for (int e = blockIdx.x * blockDim.x + threadIdx.x; e < n_edges; e += stride) {
    int s = ei[e], d = ei[n_edges + e];
    float4 a = ssrc[s], b = sdst[d];
    float e0 = a.x + b.x; e0 = e0 > 0.f ? e0 : ALPHA * e0;
    float e1 = a.y + b.y; e1 = e1 > 0.f ? e1 : ALPHA * e1;
    float e2 = a.z + b.z; e2 = e2 > 0.f ? e2 : ALPHA * e2;
    float e3 = a.w + b.w; e3 = e3 > 0.f ? e3 : ALPHA * e3;
    acc[0] += __expf(e0 - M[0]); acc[1] += __expf(e1 - M[1]);
    acc[2] += __expf(e2 - M[2]); acc[3] += __expf(e3 - M[3]);
  }
  __shared__ float red[4][4];
  int lane = threadIdx.x & 63, wv = threadIdx.x >> 6;
#pragma unroll
  for (int c = 0; c < 4; ++c)
#pragma unroll
    for (int o = 32; o; o >>= 1) acc[c] += __shfl_down(acc[c], o);
  if (lane == 0) { red[wv][0] = acc[0]; red[wv][1] = acc[1]; red[wv][2] = acc[2]; red[wv][3] = acc[3]; }
  __syncthreads();
  if (threadIdx.x < 4) {
    float v = red[0][threadIdx.x] + red[1][threadIdx.x] + red[2][threadIdx.x] + red[3][threadIdx.x];
    atomicAdd(gsum + threadIdx.x, v);
  }
}

// ---- scatter: out[dst] += softmax_w * Wh[src]; 4 threads per edge ----
__global__ __launch_bounds__(256) void k_scatter(
    const int* __restrict__ ei, const float* __restrict__ ssrc,
    const float* __restrict__ sdst, const float* __restrict__ Wh,
    const unsigned int* __restrict__ gmax, const float* __restrict__ gsum,
    float* __restrict__ out, int n_edges)
{
  int gid = blockIdx.x * blockDim.x + threadIdx.x;
  if (gid >= n_edges * N_HEADS) return;
  int e = gid >> 2, head = gid & 3;
  int s = ei[e], d = ei[n_edges + e];
  float sc = ssrc[s * N_HEADS + head] + sdst[d * N_HEADS + head];
  sc = sc > 0.f ? sc : ALPHA * sc;
  float w = __expf(sc - dec_f(gmax[head])) / gsum[head];
  const float4* src = (const float4*)(Wh + (size_t)s * OUT_C + head * 16);
  float* o = out + (size_t)d * OUT_C + head * 16;
#pragma unroll
  for (int q = 0; q < 4; ++q) {
    float4 v = src[q];
    atomicAdd(o + q * 4 + 0, w * v.x);
    atomicAdd(o + q * 4 + 1, w * v.y);
    atomicAdd(o + q * 4 + 2, w * v.z);
    atomicAdd(o + q * 4 + 3, w * v.w);
  }
}

__global__ __launch_bounds__(256) void k_relu(float4* __restrict__ out, int n4) {
  int i = blockIdx.x * blockDim.x + threadIdx.x;
  if (i < n4) {
    float4 v = out[i];
    v.x = fmaxf(v.x, 0.f); v.y = fmaxf(v.y, 0.f);
    v.z = fmaxf(v.z, 0.f); v.w = fmaxf(v.w, 0.f);
    out[i] = v;
  }
}

extern "C" void kernel_launch(void* const* d_in, const int* in_sizes, int n_in,
                              void* d_out, int out_size, void* d_ws, size_t ws_size,
                              hipStream_t stream) {
  const int*   ei    = (const int*)d_in[0];
  const float* h     = (const float*)d_in[1];
  const float* W     = (const float*)d_in[2];
  const float* a_src = (const float*)d_in[3];
  const float* a_dst = (const float*)d_in[4];
  float* out = (float*)d_out;

  const int n_edges = in_sizes[0] / 2;
  const int n_nodes = in_sizes[1] / IN_F;

  char* ws = (char*)d_ws;
  float* Wh   = (float*)ws;                                   // n_nodes*64 f32
  float* ssrc = (float*)(ws + (size_t)n_nodes * OUT_C * 4);   // n_nodes*4
  float* sdst = ssrc + (size_t)n_nodes * N_HEADS;             // n_nodes*4
  unsigned int* gmax = (unsigned int*)(sdst + (size_t)n_nodes * N_HEADS);
  float* gsum = (float*)(gmax + N_HEADS);

  hipMemsetAsync(d_out, 0, (size_t)out_size * sizeof(float), stream);
  k_init<<<1, 64, 0, stream>>>(gmax, gsum);
  k_gemm<<<(n_nodes + 63) / 64, 256, 0, stream>>>(h, W, a_src, a_dst, Wh, ssrc, sdst, n_nodes);
  k_emax<<<1024, 256, 0, stream>>>(ei, (const float4*)ssrc, (const float4*)sdst, gmax, n_edges);
  k_esum<<<1024, 256, 0, stream>>>(ei, (const float4*)ssrc, (const float4*)sdst, gmax, gsum, n_edges);
  k_scatter<<<((size_t)n_edges * N_HEADS + 255) / 256, 256, 0, stream>>>(
      ei, ssrc, sdst, Wh, gmax, gsum, out, n_edges);
  k_relu<<<(out_size / 4 + 255) / 256, 256, 0, stream>>>((float4*)out, out_size / 4);
}

// Round 2
// 287.879 us; speedup vs baseline: 13.0192x; 13.0192x over previous
//
#include <hip/hip_runtime.h>

#define IN_F 128
#define OUT_F 16
#define N_HEADS 4
#define OUT_C 64   // OUT_F * N_HEADS
#define ALPHA 0.2f

// ---- order-preserving float<->uint encoding for atomicMax on floats ----
__device__ __forceinline__ unsigned int enc_f(float f) {
  unsigned int u = __float_as_uint(f);
  return (u & 0x80000000u) ? ~u : (u | 0x80000000u);
}
__device__ __forceinline__ float dec_f(unsigned int u) {
  unsigned int b = (u & 0x80000000u) ? (u & 0x7FFFFFFFu) : ~u;
  return __uint_as_float(b);
}

__global__ __launch_bounds__(64) void k_init(unsigned int* gmax, float* gsum) {
  int t = threadIdx.x;
  if (t < N_HEADS) { gmax[t] = enc_f(-3.0e38f); gsum[t] = 0.f; }
}

// ---- GEMM: Wh = h @ W, plus per-node attention scores s_src, s_dst ----
__global__ __launch_bounds__(256) void k_gemm(
    const float* __restrict__ h, const float* __restrict__ W,
    const float* __restrict__ a_src, const float* __restrict__ a_dst,
    float* __restrict__ Wh, float* __restrict__ ssrc, float* __restrict__ sdst,
    int n_nodes)
{
  __shared__ __align__(16) float Wl[IN_F * OUT_C];   // 32 KB
  __shared__ __align__(16) float hl[64 * 132];       // pad 128->132
  __shared__ float al[2][OUT_C];
  const int t = threadIdx.x;
  const int row0 = blockIdx.x * 64;

  for (int i = t; i < IN_F * OUT_C / 4; i += 256)
    ((float4*)Wl)[i] = ((const float4*)W)[i];
  if (t < OUT_C) { al[0][t] = a_src[t]; al[1][t] = a_dst[t]; }
  for (int i = t; i < 64 * IN_F / 4; i += 256) {
    int r = i >> 5, c4 = i & 31;
    int gr = row0 + r;
    float4 v = (gr < n_nodes) ? ((const float4*)(h + (size_t)gr * IN_F))[c4]
                              : make_float4(0.f, 0.f, 0.f, 0.f);
    *(float4*)&hl[r * 132 + c4 * 4] = v;
  }
  __syncthreads();

  const int r = t >> 2, head = t & 3;
  const int row = row0 + r;
  if (row >= n_nodes) return;

  float acc[16];
#pragma unroll
  for (int f = 0; f < 16; ++f) acc[f] = 0.f;
  const float* wcol = Wl + head * 16;
  const float* hr = hl + r * 132;
#pragma unroll 4
  for (int k = 0; k < IN_F; ++k) {
    float hv = hr[k];
#pragma unroll
    for (int q = 0; q < 4; ++q) {
      float4 w = *(const float4*)(wcol + k * OUT_C + q * 4);
      acc[q * 4 + 0] += hv * w.x;
      acc[q * 4 + 1] += hv * w.y;
      acc[q * 4 + 2] += hv * w.z;
      acc[q * 4 + 3] += hv * w.w;
    }
  }
  float s0 = 0.f, s1 = 0.f;
#pragma unroll
  for (int f = 0; f < 16; ++f) {
    s0 += acc[f] * al[0][head * 16 + f];
    s1 += acc[f] * al[1][head * 16 + f];
  }
  float* o = Wh + (size_t)row * OUT_C + head * 16;
#pragma unroll
  for (int q = 0; q < 4; ++q)
    ((float4*)o)[q] = make_float4(acc[q * 4], acc[q * 4 + 1], acc[q * 4 + 2], acc[q * 4 + 3]);
  ssrc[row * N_HEADS + head] = s0;
  sdst[row * N_HEADS + head] = s1;
}

// ---- per-head global max over edges + dst-degree histogram ----
__global__ __launch_bounds__(256) void k_emax(
    const int* __restrict__ ei, const float4* __restrict__ ssrc,
    const float4* __restrict__ sdst, unsigned int* __restrict__ gmax,
    int* __restrict__ count, int n_edges)
{
  float m[4] = {-3.0e38f, -3.0e38f, -3.0e38f, -3.0e38f};
  int stride = gridDim.x * blockDim.x;
  for (int e = blockIdx.x * blockDim.x + threadIdx.x; e < n_edges; e += stride) {
    int s = ei[e], d = ei[n_edges + e];
    atomicAdd(count + d, 1);
    float4 a = ssrc[s], b = sdst[d];
    float e0 = a.x + b.x; e0 = e0 > 0.f ? e0 : ALPHA * e0;
    float e1 = a.y + b.y; e1 = e1 > 0.f ? e1 : ALPHA * e1;
    float e2 = a.z + b.z; e2 = e2 > 0.f ? e2 : ALPHA * e2;
    float e3 = a.w + b.w; e3 = e3 > 0.f ? e3 : ALPHA * e3;
    m[0] = fmaxf(m[0], e0); m[1] = fmaxf(m[1], e1);
    m[2] = fmaxf(m[2], e2); m[3] = fmaxf(m[3], e3);
  }
  __shared__ float red[4][4];
  int lane = threadIdx.x & 63, wv = threadIdx.x >> 6;
#pragma unroll
  for (int c = 0; c < 4; ++c)
#pragma unroll
    for (int o = 32; o; o >>= 1) m[c] = fmaxf(m[c], __shfl_down(m[c], o));
  if (lane == 0) { red[wv][0] = m[0]; red[wv][1] = m[1]; red[wv][2] = m[2]; red[wv][3] = m[3]; }
  __syncthreads();
  if (threadIdx.x < 4) {
    float v = fmaxf(fmaxf(red[0][threadIdx.x], red[1][threadIdx.x]),
                    fmaxf(red[2][threadIdx.x], red[3][threadIdx.x]));
    atomicMax(gmax + threadIdx.x, enc_f(v));
  }
}

// ---- per-head sum of exp(e - max) ----
__global__ __launch_bounds__(256) void k_esum(
    const int* __restrict__ ei, const float4* __restrict__ ssrc,
    const float4* __restrict__ sdst, const unsigned int* __restrict__ gmax,
    float* __restrict__ gsum, int n_edges)
{
  float M[4];
#pragma unroll
  for (int c = 0; c < 4; ++c) M[c] = dec_f(gmax[c]);
  float acc[4] = {0.f, 0.f, 0.f, 0.f};
  int stride = gridDim.x * blockDim.x;
  for (int e = blockIdx.x * blockDim.x + threadIdx.x; e < n_edges; e += stride) {
    int s = ei[e], d = ei[n_edges + e];
    float4 a = ssrc[s], b = sdst[d];
    float e0 = a.x + b.x; e0 = e0 > 0.f ? e0 : ALPHA * e0;
    float e1 = a.y + b.y; e1 = e1 > 0.f ? e1 : ALPHA * e1;
    float e2 = a.z + b.z; e2 = e2 > 0.f ? e2 : ALPHA * e2;
    float e3 = a.w + b.w; e3 = e3 > 0.f ? e3 : ALPHA * e3;
    acc[0] += __expf(e0 - M[0]); acc[1] += __expf(e1 - M[1]);
    acc[2] += __expf(e2 - M[2]); acc[3] += __expf(e3 - M[3]);
  }
  __shared__ float red[4][4];
  int lane = threadIdx.x & 63, wv = threadIdx.x >> 6;
#pragma unroll
  for (int c = 0; c < 4; ++c)
#pragma unroll
    for (int o = 32; o; o >>= 1) acc[c] += __shfl_down(acc[c], o);
  if (lane == 0) { red[wv][0] = acc[0]; red[wv][1] = acc[1]; red[wv][2] = acc[2]; red[wv][3] = acc[3]; }
  __syncthreads();
  if (threadIdx.x < 4) {
    float v = red[0][threadIdx.x] + red[1][threadIdx.x] + red[2][threadIdx.x] + red[3][threadIdx.x];
    atomicAdd(gsum + threadIdx.x, v);
  }
}

// ---- two-level exclusive scan of counts (N up to 65536) ----
__global__ __launch_bounds__(1024) void k_scan1(
    const int* __restrict__ count, int* __restrict__ offs, int* __restrict__ tsum, int n)
{
  __shared__ int sd[1024];
  int t = threadIdx.x;
  int i = blockIdx.x * 1024 + t;
  int c = (i < n) ? count[i] : 0;
  sd[t] = c;
  __syncthreads();
#pragma unroll
  for (int off = 1; off < 1024; off <<= 1) {
    int v = (t >= off) ? sd[t - off] : 0;
    __syncthreads();
    sd[t] += v;
    __syncthreads();
  }
  if (i < n) offs[i] = sd[t] - c;           // exclusive within tile
  if (t == 1023) tsum[blockIdx.x] = sd[1023];
}

__global__ __launch_bounds__(64) void k_scan2(int* __restrict__ tsum, int* __restrict__ tbase, int nb) {
  if (threadIdx.x == 0) {
    int run = 0;
    for (int b = 0; b < nb; ++b) { tbase[b] = run; run += tsum[b]; }
  }
}

__global__ __launch_bounds__(1024) void k_scan3(
    int* __restrict__ offs, const int* __restrict__ tbase,
    int* __restrict__ cursor, int n, int n_edges)
{
  int i = blockIdx.x * 1024 + threadIdx.x;
  if (i < n) {
    int o = offs[i] + tbase[i >> 10];
    offs[i] = o;
    cursor[i] = o;
  }
  if (i == 0) offs[n] = n_edges;
}

// ---- bucket edges by dst ----
__global__ __launch_bounds__(256) void k_bucket(
    const int* __restrict__ ei, int* __restrict__ cursor,
    int* __restrict__ sorted_src, int n_edges)
{
  int stride = gridDim.x * blockDim.x;
  for (int e = blockIdx.x * blockDim.x + threadIdx.x; e < n_edges; e += stride) {
    int s = ei[e], d = ei[n_edges + e];
    int pos = atomicAdd(cursor + d, 1);
    sorted_src[pos] = s;
  }
}

// ---- aggregate: one wave per dst node, lane = output channel; fused ReLU ----
__global__ __launch_bounds__(256) void k_agg(
    const int* __restrict__ offs, const int* __restrict__ sorted_src,
    const float* __restrict__ ssrc, const float* __restrict__ sdst,
    const float* __restrict__ Wh, const unsigned int* __restrict__ gmax,
    const float* __restrict__ gsum, float* __restrict__ out, int n_nodes)
{
  int d = blockIdx.x * 4 + (threadIdx.x >> 6);
  if (d >= n_nodes) return;
  int lane = threadIdx.x & 63;
  int head = lane >> 4;
  float M = dec_f(gmax[head]);
  float inv = 1.f / gsum[head];
  float sd = sdst[d * N_HEADS + head];
  int beg = offs[d], end = offs[d + 1];
  float acc = 0.f;
  for (int j = beg; j < end; ++j) {
    int s = sorted_src[j];
    float sc = ssrc[s * N_HEADS + head] + sd;
    sc = sc > 0.f ? sc : ALPHA * sc;
    float w = __expf(sc - M) * inv;
    acc += w * Wh[(size_t)s * OUT_C + lane];
  }
  out[(size_t)d * OUT_C + lane] = fmaxf(acc, 0.f);
}

extern "C" void kernel_launch(void* const* d_in, const int* in_sizes, int n_in,
                              void* d_out, int out_size, void* d_ws, size_t ws_size,
                              hipStream_t stream) {
  const int*   ei    = (const int*)d_in[0];
  const float* h     = (const float*)d_in[1];
  const float* W     = (const float*)d_in[2];
  const float* a_src = (const float*)d_in[3];
  const float* a_dst = (const float*)d_in[4];
  float* out = (float*)d_out;

  const int n_edges = in_sizes[0] / 2;
  const int n_nodes = in_sizes[1] / IN_F;
  const int ntiles  = (n_nodes + 1023) / 1024;

  char* ws = (char*)d_ws;
  size_t off = 0;
  auto alloc = [&](size_t bytes) { void* p = ws + off; off = (off + bytes + 15) & ~(size_t)15; return p; };
  float* Wh          = (float*)alloc((size_t)n_nodes * OUT_C * 4);
  float* ssrc        = (float*)alloc((size_t)n_nodes * N_HEADS * 4);
  float* sdst        = (float*)alloc((size_t)n_nodes * N_HEADS * 4);
  unsigned int* gmax = (unsigned int*)alloc(N_HEADS * 4);
  float* gsum        = (float*)alloc(N_HEADS * 4);
  int* count         = (int*)alloc((size_t)n_nodes * 4);
  int* offs          = (int*)alloc(((size_t)n_nodes + 1) * 4);
  int* tsum          = (int*)alloc((size_t)ntiles * 4);
  int* tbase         = (int*)alloc((size_t)ntiles * 4);
  int* cursor        = (int*)alloc((size_t)n_nodes * 4);
  int* sorted_src    = (int*)alloc((size_t)n_edges * 4);

  hipMemsetAsync(count, 0, (size_t)n_nodes * 4, stream);
  k_init<<<1, 64, 0, stream>>>(gmax, gsum);
  k_gemm<<<(n_nodes + 63) / 64, 256, 0, stream>>>(h, W, a_src, a_dst, Wh, ssrc, sdst, n_nodes);
  k_emax<<<1024, 256, 0, stream>>>(ei, (const float4*)ssrc, (const float4*)sdst, gmax, count, n_edges);
  k_esum<<<1024, 256, 0, stream>>>(ei, (const float4*)ssrc, (const float4*)sdst, gmax, gsum, n_edges);
  k_scan1<<<ntiles, 1024, 0, stream>>>(count, offs, tsum, n_nodes);
  k_scan2<<<1, 64, 0, stream>>>(tsum, tbase, ntiles);
  k_scan3<<<ntiles, 1024, 0, stream>>>(offs, tbase, cursor, n_nodes, n_edges);
  k_bucket<<<1024, 256, 0, stream>>>(ei, cursor, sorted_src, n_edges);
  k_agg<<<(n_nodes + 3) / 4, 256, 0, stream>>>(offs, sorted_src, ssrc, sdst, Wh, gmax, gsum, out, n_nodes);
}

// Round 3
// 278.930 us; speedup vs baseline: 13.4369x; 1.0321x over previous
//
#include <hip/hip_runtime.h>

#define IN_F 128
#define OUT_F 16
#define N_HEADS 4
#define OUT_C 64   // OUT_F * N_HEADS
#define ALPHA 0.2f

// ---- order-preserving float<->uint encoding for atomicMax on floats ----
__device__ __forceinline__ unsigned int enc_f(float f) {
  unsigned int u = __float_as_uint(f);
  return (u & 0x80000000u) ? ~u : (u | 0x80000000u);
}
__device__ __forceinline__ float dec_f(unsigned int u) {
  unsigned int b = (u & 0x80000000u) ? (u & 0x7FFFFFFFu) : ~u;
  return __uint_as_float(b);
}

__global__ __launch_bounds__(64) void k_init(unsigned int* gmax_s, unsigned int* gmax_d,
                                             float* gsum) {
  int t = threadIdx.x;
  if (t < N_HEADS) {
    gmax_s[t] = enc_f(-3.0e38f);
    gmax_d[t] = enc_f(-3.0e38f);
    gsum[t] = 0.f;
  }
}

// ---- dst-degree histogram (dst column only: 4 MB) ----
__global__ __launch_bounds__(256) void k_hist(
    const int* __restrict__ dst, int* __restrict__ count, int n_edges)
{
  int n4 = n_edges >> 2;
  int stride = gridDim.x * blockDim.x;
  for (int i = blockIdx.x * blockDim.x + threadIdx.x; i < n4; i += stride) {
    int4 d = ((const int4*)dst)[i];
    atomicAdd(count + d.x, 1);
    atomicAdd(count + d.y, 1);
    atomicAdd(count + d.z, 1);
    atomicAdd(count + d.w, 1);
  }
  int t = blockIdx.x * blockDim.x + threadIdx.x;
  int e = (n4 << 2) + t;
  if (e < n_edges) atomicAdd(count + dst[e], 1);
}

// ---- GEMM: Wh = h @ W, scores s_src/s_dst, + per-head score-max epilogue ----
__global__ __launch_bounds__(256) void k_gemm(
    const float* __restrict__ h, const float* __restrict__ W,
    const float* __restrict__ a_src, const float* __restrict__ a_dst,
    float* __restrict__ Wh, float* __restrict__ ssrc, float* __restrict__ sdst,
    unsigned int* __restrict__ gmax_s, unsigned int* __restrict__ gmax_d,
    int n_nodes)
{
  __shared__ __align__(16) float Wl[IN_F * OUT_C];   // 32 KB
  __shared__ __align__(16) float hl[64 * 132];       // pad 128->132
  __shared__ float al[2][OUT_C];
  const int t = threadIdx.x;
  const int row0 = blockIdx.x * 64;

  for (int i = t; i < IN_F * OUT_C / 4; i += 256)
    ((float4*)Wl)[i] = ((const float4*)W)[i];
  if (t < OUT_C) { al[0][t] = a_src[t]; al[1][t] = a_dst[t]; }
  for (int i = t; i < 64 * IN_F / 4; i += 256) {
    int r = i >> 5, c4 = i & 31;
    int gr = row0 + r;
    float4 v = (gr < n_nodes) ? ((const float4*)(h + (size_t)gr * IN_F))[c4]
                              : make_float4(0.f, 0.f, 0.f, 0.f);
    *(float4*)&hl[r * 132 + c4 * 4] = v;
  }
  __syncthreads();

  const int r = t >> 2, head = t & 3;
  const int row = row0 + r;
  const bool valid = row < n_nodes;

  float acc[16];
#pragma unroll
  for (int f = 0; f < 16; ++f) acc[f] = 0.f;
  const float* wcol = Wl + head * 16;
  const float* hr = hl + r * 132;
#pragma unroll 4
  for (int k = 0; k < IN_F; ++k) {
    float hv = hr[k];
#pragma unroll
    for (int q = 0; q < 4; ++q) {
      float4 w = *(const float4*)(wcol + k * OUT_C + q * 4);
      acc[q * 4 + 0] += hv * w.x;
      acc[q * 4 + 1] += hv * w.y;
      acc[q * 4 + 2] += hv * w.z;
      acc[q * 4 + 3] += hv * w.w;
    }
  }
  float s0 = 0.f, s1 = 0.f;
#pragma unroll
  for (int f = 0; f < 16; ++f) {
    s0 += acc[f] * al[0][head * 16 + f];
    s1 += acc[f] * al[1][head * 16 + f];
  }
  if (valid) {
    float* o = Wh + (size_t)row * OUT_C + head * 16;
#pragma unroll
    for (int q = 0; q < 4; ++q)
      ((float4*)o)[q] = make_float4(acc[q * 4], acc[q * 4 + 1], acc[q * 4 + 2], acc[q * 4 + 3]);
    ssrc[row * N_HEADS + head] = s0;
    sdst[row * N_HEADS + head] = s1;
  } else {
    s0 = -3.0e38f; s1 = -3.0e38f;
  }
  // wave-reduce max over lanes with same (lane&3)==head; lanes 0..3 hold result
#pragma unroll
  for (int o = 4; o < 64; o <<= 1) {
    s0 = fmaxf(s0, __shfl_down(s0, o));
    s1 = fmaxf(s1, __shfl_down(s1, o));
  }
  int lane = t & 63;
  if (lane < 4) {
    atomicMax(gmax_s + lane, enc_f(s0));
    atomicMax(gmax_d + lane, enc_f(s1));
  }
}

// ---- fused: per-edge weight numerators + gsum + bucket-by-dst ----
__global__ __launch_bounds__(256) void k_esb(
    const int* __restrict__ ei, const float4* __restrict__ ssrc4,
    const float4* __restrict__ sdst4, const unsigned int* __restrict__ gmax_s,
    const unsigned int* __restrict__ gmax_d, float* __restrict__ gsum,
    int* __restrict__ cursor, int* __restrict__ sorted_src,
    float4* __restrict__ sorted_w, int n_edges)
{
  float M[4];
#pragma unroll
  for (int c = 0; c < 4; ++c) {
    float m = dec_f(gmax_s[c]) + dec_f(gmax_d[c]);   // upper bound on edge max
    M[c] = m > 0.f ? m : ALPHA * m;                  // LReLU monotone
  }
  float acc[4] = {0.f, 0.f, 0.f, 0.f};
  const int* srcp = ei;
  const int* dstp = ei + n_edges;
  int n4 = n_edges >> 2;
  int stride = gridDim.x * blockDim.x;
  int tid = blockIdx.x * blockDim.x + threadIdx.x;

  for (int i = tid; i < n4; i += stride) {
    int4 sv = ((const int4*)srcp)[i];
    int4 dv = ((const int4*)dstp)[i];
    int ss[4] = {sv.x, sv.y, sv.z, sv.w};
    int dd[4] = {dv.x, dv.y, dv.z, dv.w};
#pragma unroll
    for (int u = 0; u < 4; ++u) {
      float4 a = ssrc4[ss[u]];
      float4 b = sdst4[dd[u]];
      float e0 = a.x + b.x; e0 = e0 > 0.f ? e0 : ALPHA * e0;
      float e1 = a.y + b.y; e1 = e1 > 0.f ? e1 : ALPHA * e1;
      float e2 = a.z + b.z; e2 = e2 > 0.f ? e2 : ALPHA * e2;
      float e3 = a.w + b.w; e3 = e3 > 0.f ? e3 : ALPHA * e3;
      float4 w;
      w.x = __expf(e0 - M[0]); w.y = __expf(e1 - M[1]);
      w.z = __expf(e2 - M[2]); w.w = __expf(e3 - M[3]);
      acc[0] += w.x; acc[1] += w.y; acc[2] += w.z; acc[3] += w.w;
      int pos = atomicAdd(cursor + dd[u], 1);
      sorted_src[pos] = ss[u];
      sorted_w[pos] = w;
    }
  }
  // tail
  int e = (n4 << 2) + tid;
  if (e < n_edges) {
    int s = srcp[e], d = dstp[e];
    float4 a = ssrc4[s];
    float4 b = sdst4[d];
    float e0 = a.x + b.x; e0 = e0 > 0.f ? e0 : ALPHA * e0;
    float e1 = a.y + b.y; e1 = e1 > 0.f ? e1 : ALPHA * e1;
    float e2 = a.z + b.z; e2 = e2 > 0.f ? e2 : ALPHA * e2;
    float e3 = a.w + b.w; e3 = e3 > 0.f ? e3 : ALPHA * e3;
    float4 w;
    w.x = __expf(e0 - M[0]); w.y = __expf(e1 - M[1]);
    w.z = __expf(e2 - M[2]); w.w = __expf(e3 - M[3]);
    acc[0] += w.x; acc[1] += w.y; acc[2] += w.z; acc[3] += w.w;
    int pos = atomicAdd(cursor + d, 1);
    sorted_src[pos] = s;
    sorted_w[pos] = w;
  }

  __shared__ float red[4][4];
  int lane = threadIdx.x & 63, wv = threadIdx.x >> 6;
#pragma unroll
  for (int c = 0; c < 4; ++c)
#pragma unroll
    for (int o = 32; o; o >>= 1) acc[c] += __shfl_down(acc[c], o);
  if (lane == 0) { red[wv][0] = acc[0]; red[wv][1] = acc[1]; red[wv][2] = acc[2]; red[wv][3] = acc[3]; }
  __syncthreads();
  if (threadIdx.x < 4) {
    float v = red[0][threadIdx.x] + red[1][threadIdx.x] + red[2][threadIdx.x] + red[3][threadIdx.x];
    atomicAdd(gsum + threadIdx.x, v);
  }
}

// ---- two-level exclusive scan of counts ----
__global__ __launch_bounds__(1024) void k_scan1(
    const int* __restrict__ count, int* __restrict__ offs, int* __restrict__ tsum, int n)
{
  __shared__ int sd[1024];
  int t = threadIdx.x;
  int i = blockIdx.x * 1024 + t;
  int c = (i < n) ? count[i] : 0;
  sd[t] = c;
  __syncthreads();
#pragma unroll
  for (int off = 1; off < 1024; off <<= 1) {
    int v = (t >= off) ? sd[t - off] : 0;
    __syncthreads();
    sd[t] += v;
    __syncthreads();
  }
  if (i < n) offs[i] = sd[t] - c;
  if (t == 1023) tsum[blockIdx.x] = sd[1023];
}

__global__ __launch_bounds__(64) void k_scan2(int* __restrict__ tsum, int* __restrict__ tbase, int nb) {
  if (threadIdx.x == 0) {
    int run = 0;
    for (int b = 0; b < nb; ++b) { tbase[b] = run; run += tsum[b]; }
  }
}

__global__ __launch_bounds__(1024) void k_scan3(
    int* __restrict__ offs, const int* __restrict__ tbase,
    int* __restrict__ cursor, int n, int n_edges)
{
  int i = blockIdx.x * 1024 + threadIdx.x;
  if (i < n) {
    int o = offs[i] + tbase[i >> 10];
    offs[i] = o;
    cursor[i] = o;
  }
  if (i == 0) offs[n] = n_edges;
}

// ---- aggregate: one wave per dst, lane = channel; weights precomputed ----
__global__ __launch_bounds__(256) void k_agg(
    const int* __restrict__ offs, const int* __restrict__ sorted_src,
    const float4* __restrict__ sorted_w, const float* __restrict__ Wh,
    const float* __restrict__ gsum, float* __restrict__ out, int n_nodes)
{
  int d = blockIdx.x * 4 + (threadIdx.x >> 6);
  if (d >= n_nodes) return;
  int lane = threadIdx.x & 63;
  int head = lane >> 4;
  int beg = offs[d], end = offs[d + 1];
  float acc = 0.f;
  int j = beg;
  for (; j + 4 <= end; j += 4) {
    int s[4];
    float4 w[4];
#pragma unroll
    for (int u = 0; u < 4; ++u) { s[u] = sorted_src[j + u]; w[u] = sorted_w[j + u]; }
#pragma unroll
    for (int u = 0; u < 4; ++u) {
      float v = Wh[(size_t)s[u] * OUT_C + lane];
      float ww = head == 0 ? w[u].x : head == 1 ? w[u].y : head == 2 ? w[u].z : w[u].w;
      acc += ww * v;
    }
  }
  for (; j < end; ++j) {
    int s = sorted_src[j];
    float4 w4 = sorted_w[j];
    float ww = head == 0 ? w4.x : head == 1 ? w4.y : head == 2 ? w4.z : w4.w;
    acc += ww * Wh[(size_t)s * OUT_C + lane];
  }
  out[(size_t)d * OUT_C + lane] = fmaxf(acc / gsum[head], 0.f);
}

extern "C" void kernel_launch(void* const* d_in, const int* in_sizes, int n_in,
                              void* d_out, int out_size, void* d_ws, size_t ws_size,
                              hipStream_t stream) {
  const int*   ei    = (const int*)d_in[0];
  const float* h     = (const float*)d_in[1];
  const float* W     = (const float*)d_in[2];
  const float* a_src = (const float*)d_in[3];
  const float* a_dst = (const float*)d_in[4];
  float* out = (float*)d_out;

  const int n_edges = in_sizes[0] / 2;
  const int n_nodes = in_sizes[1] / IN_F;
  const int ntiles  = (n_nodes + 1023) / 1024;

  char* ws = (char*)d_ws;
  size_t off = 0;
  auto alloc = [&](size_t bytes) { void* p = ws + off; off = (off + bytes + 15) & ~(size_t)15; return p; };
  float* Wh           = (float*)alloc((size_t)n_nodes * OUT_C * 4);
  float* ssrc         = (float*)alloc((size_t)n_nodes * N_HEADS * 4);
  float* sdst         = (float*)alloc((size_t)n_nodes * N_HEADS * 4);
  unsigned int* gmax_s= (unsigned int*)alloc(N_HEADS * 4);
  unsigned int* gmax_d= (unsigned int*)alloc(N_HEADS * 4);
  float* gsum         = (float*)alloc(N_HEADS * 4);
  int* count          = (int*)alloc((size_t)n_nodes * 4);
  int* offs           = (int*)alloc(((size_t)n_nodes + 1) * 4);
  int* tsum           = (int*)alloc((size_t)ntiles * 4);
  int* tbase          = (int*)alloc((size_t)ntiles * 4);
  int* cursor         = (int*)alloc((size_t)n_nodes * 4);
  float4* sorted_w    = (float4*)alloc((size_t)n_edges * 16);
  int* sorted_src     = (int*)alloc((size_t)n_edges * 4);

  hipMemsetAsync(count, 0, (size_t)n_nodes * 4, stream);
  k_init<<<1, 64, 0, stream>>>(gmax_s, gmax_d, gsum);
  k_hist<<<1024, 256, 0, stream>>>(ei + n_edges, count, n_edges);
  k_gemm<<<(n_nodes + 63) / 64, 256, 0, stream>>>(h, W, a_src, a_dst, Wh, ssrc, sdst,
                                                  gmax_s, gmax_d, n_nodes);
  k_scan1<<<ntiles, 1024, 0, stream>>>(count, offs, tsum, n_nodes);
  k_scan2<<<1, 64, 0, stream>>>(tsum, tbase, ntiles);
  k_scan3<<<ntiles, 1024, 0, stream>>>(offs, tbase, cursor, n_nodes, n_edges);
  k_esb<<<1024, 256, 0, stream>>>(ei, (const float4*)ssrc, (const float4*)sdst,
                                  gmax_s, gmax_d, gsum, cursor, sorted_src, sorted_w, n_edges);
  k_agg<<<(n_nodes + 3) / 4, 256, 0, stream>>>(offs, sorted_src, (const float4*)sorted_w,
                                               Wh, gsum, out, n_nodes);
}

// Round 4
// 213.889 us; speedup vs baseline: 17.5229x; 1.3041x over previous
//
#include <hip/hip_runtime.h>
#include <hip/hip_bf16.h>

#define IN_F 128
#define OUT_F 16
#define N_HEADS 4
#define OUT_C 64   // OUT_F * N_HEADS
#define ALPHA 0.2f

typedef __attribute__((ext_vector_type(8))) short bf16x8;
typedef __attribute__((ext_vector_type(4))) float f32x4;

// ---- order-preserving float<->uint encoding for atomicMax on floats ----
__device__ __forceinline__ unsigned int enc_f(float f) {
  unsigned int u = __float_as_uint(f);
  return (u & 0x80000000u) ? ~u : (u | 0x80000000u);
}
__device__ __forceinline__ float dec_f(unsigned int u) {
  unsigned int b = (u & 0x80000000u) ? (u & 0x7FFFFFFFu) : ~u;
  return __uint_as_float(b);
}

__device__ __forceinline__ ushort f2bf(float f) {
  union { __hip_bfloat16 b; ushort u; } cv;
  cv.b = __float2bfloat16(f);
  return cv.u;
}

__global__ __launch_bounds__(64) void k_init(unsigned int* gmax_s, unsigned int* gmax_d,
                                             float* gsum) {
  int t = threadIdx.x;
  if (t < N_HEADS) {
    gmax_s[t] = enc_f(-3.0e38f);
    gmax_d[t] = enc_f(-3.0e38f);
    gsum[t] = 0.f;
  }
}

// ---- pack W (fp32 [128][64]) into B-fragment lane layout, bf16 ----
// Wp[(ks*4+ct)*64 + lane] = 8 bf16: W[ks*32+(lane>>4)*8+j][ct*16+(lane&15)]
__global__ __launch_bounds__(64) void k_pack(const float* __restrict__ W,
                                             uint4* __restrict__ Wp) {
  int lane = threadIdx.x;
  int cl = lane & 15, kg = lane >> 4;
#pragma unroll
  for (int ks = 0; ks < 4; ++ks)
#pragma unroll
    for (int ct = 0; ct < 4; ++ct) {
      int c = ct * 16 + cl;
      int k0 = ks * 32 + kg * 8;
      union { ushort u[8]; uint4 q; } P;
#pragma unroll
      for (int j = 0; j < 8; ++j) P.u[j] = f2bf(W[(k0 + j) * OUT_C + c]);
      Wp[(ks * 4 + ct) * 64 + lane] = P.q;
    }
}

// ---- MFMA GEMM: Wh = h @ W  (bf16 inputs, fp32 accum/output) ----
// wave: 16 rows x 64 cols; 4 k-steps x 4 col-tiles of mfma 16x16x32.
__global__ __launch_bounds__(256) void k_mm(
    const float* __restrict__ h, const uint4* __restrict__ Wp,
    float* __restrict__ Wh, int n_nodes)
{
  const int wid = threadIdx.x >> 6, lane = threadIdx.x & 63;
  const int r0 = blockIdx.x * 64 + wid * 16;
  const int arow = r0 + (lane & 15);
  const int rclamp = arow < n_nodes ? arow : n_nodes - 1;
  const float* hrow = h + (size_t)rclamp * IN_F + (lane >> 4) * 8;

  f32x4 acc[4];
#pragma unroll
  for (int ct = 0; ct < 4; ++ct) acc[ct] = (f32x4){0.f, 0.f, 0.f, 0.f};

#pragma unroll
  for (int ks = 0; ks < 4; ++ks) {
    float4 a0 = *(const float4*)(hrow + ks * 32);
    float4 a1 = *(const float4*)(hrow + ks * 32 + 4);
    union { ushort u[8]; bf16x8 v; } A;
    A.u[0] = f2bf(a0.x); A.u[1] = f2bf(a0.y); A.u[2] = f2bf(a0.z); A.u[3] = f2bf(a0.w);
    A.u[4] = f2bf(a1.x); A.u[5] = f2bf(a1.y); A.u[6] = f2bf(a1.z); A.u[7] = f2bf(a1.w);
#pragma unroll
    for (int ct = 0; ct < 4; ++ct) {
      union { uint4 q; bf16x8 v; } B;
      B.q = Wp[(ks * 4 + ct) * 64 + lane];
      acc[ct] = __builtin_amdgcn_mfma_f32_16x16x32_bf16(A.v, B.v, acc[ct], 0, 0, 0);
    }
  }

  // D layout: col = lane&15, row = r0 + (lane>>4)*4 + j
  const int rbase = r0 + (lane >> 4) * 4;
#pragma unroll
  for (int ct = 0; ct < 4; ++ct) {
    int c = ct * 16 + (lane & 15);
#pragma unroll
    for (int j = 0; j < 4; ++j) {
      int r = rbase + j;
      if (r < n_nodes) Wh[(size_t)r * OUT_C + c] = acc[ct][j];
    }
  }
}

// ---- scores s_src/s_dst from Wh + per-head global max of each ----
__global__ __launch_bounds__(256) void k_score(
    const float* __restrict__ Wh, const float* __restrict__ a_src,
    const float* __restrict__ a_dst, float4* __restrict__ ssrc4,
    float4* __restrict__ sdst4, unsigned int* __restrict__ gmax_s,
    unsigned int* __restrict__ gmax_d, int n_nodes)
{
  __shared__ float asl[OUT_C], adl[OUT_C];
  __shared__ float redS[4][N_HEADS], redD[4][N_HEADS];
  int t = threadIdx.x;
  if (t < OUT_C) { asl[t] = a_src[t]; adl[t] = a_dst[t]; }
  __syncthreads();
  int node = blockIdx.x * 256 + t;
  float s[N_HEADS], d[N_HEADS];
#pragma unroll
  for (int hh = 0; hh < N_HEADS; ++hh) { s[hh] = -3.0e38f; d[hh] = -3.0e38f; }
  if (node < n_nodes) {
    const float4* row = (const float4*)(Wh + (size_t)node * OUT_C);
#pragma unroll
    for (int hh = 0; hh < N_HEADS; ++hh) {
      float ps = 0.f, pd = 0.f;
#pragma unroll
      for (int q = 0; q < 4; ++q) {
        float4 v = row[hh * 4 + q];
        const float* as = asl + hh * 16 + q * 4;
        const float* ad = adl + hh * 16 + q * 4;
        ps += v.x * as[0] + v.y * as[1] + v.z * as[2] + v.w * as[3];
        pd += v.x * ad[0] + v.y * ad[1] + v.z * ad[2] + v.w * ad[3];
      }
      s[hh] = ps; d[hh] = pd;
    }
    ssrc4[node] = make_float4(s[0], s[1], s[2], s[3]);
    sdst4[node] = make_float4(d[0], d[1], d[2], d[3]);
  }
  int lane = t & 63, wv = t >> 6;
#pragma unroll
  for (int hh = 0; hh < N_HEADS; ++hh) {
#pragma unroll
    for (int o = 32; o; o >>= 1) {
      s[hh] = fmaxf(s[hh], __shfl_down(s[hh], o));
      d[hh] = fmaxf(d[hh], __shfl_down(d[hh], o));
    }
  }
  if (lane == 0) {
#pragma unroll
    for (int hh = 0; hh < N_HEADS; ++hh) { redS[wv][hh] = s[hh]; redD[wv][hh] = d[hh]; }
  }
  __syncthreads();
  if (t < N_HEADS) {
    float ms = fmaxf(fmaxf(redS[0][t], redS[1][t]), fmaxf(redS[2][t], redS[3][t]));
    float md = fmaxf(fmaxf(redD[0][t], redD[1][t]), fmaxf(redD[2][t], redD[3][t]));
    atomicMax(gmax_s + t, enc_f(ms));
    atomicMax(gmax_d + t, enc_f(md));
  }
}

// ---- dst-degree histogram (dst column only: 4 MB) ----
__global__ __launch_bounds__(256) void k_hist(
    const int* __restrict__ dst, int* __restrict__ count, int n_edges)
{
  int n4 = n_edges >> 2;
  int stride = gridDim.x * blockDim.x;
  for (int i = blockIdx.x * blockDim.x + threadIdx.x; i < n4; i += stride) {
    int4 d = ((const int4*)dst)[i];
    atomicAdd(count + d.x, 1);
    atomicAdd(count + d.y, 1);
    atomicAdd(count + d.z, 1);
    atomicAdd(count + d.w, 1);
  }
  int t = blockIdx.x * blockDim.x + threadIdx.x;
  int e = (n4 << 2) + t;
  if (e < n_edges) atomicAdd(count + dst[e], 1);
}

// ---- fused: per-edge weight numerators + gsum + bucket-by-dst ----
__global__ __launch_bounds__(256) void k_esb(
    const int* __restrict__ ei, const float4* __restrict__ ssrc4,
    const float4* __restrict__ sdst4, const unsigned int* __restrict__ gmax_s,
    const unsigned int* __restrict__ gmax_d, float* __restrict__ gsum,
    int* __restrict__ cursor, int* __restrict__ sorted_src,
    float4* __restrict__ sorted_w, int n_edges)
{
  float M[4];
#pragma unroll
  for (int c = 0; c < 4; ++c) {
    float m = dec_f(gmax_s[c]) + dec_f(gmax_d[c]);   // upper bound on edge max
    M[c] = m > 0.f ? m : ALPHA * m;                  // LReLU monotone
  }
  float acc[4] = {0.f, 0.f, 0.f, 0.f};
  const int* srcp = ei;
  const int* dstp = ei + n_edges;
  int n4 = n_edges >> 2;
  int stride = gridDim.x * blockDim.x;
  int tid = blockIdx.x * blockDim.x + threadIdx.x;

  for (int i = tid; i < n4; i += stride) {
    int4 sv = ((const int4*)srcp)[i];
    int4 dv = ((const int4*)dstp)[i];
    int ss[4] = {sv.x, sv.y, sv.z, sv.w};
    int dd[4] = {dv.x, dv.y, dv.z, dv.w};
#pragma unroll
    for (int u = 0; u < 4; ++u) {
      float4 a = ssrc4[ss[u]];
      float4 b = sdst4[dd[u]];
      float e0 = a.x + b.x; e0 = e0 > 0.f ? e0 : ALPHA * e0;
      float e1 = a.y + b.y; e1 = e1 > 0.f ? e1 : ALPHA * e1;
      float e2 = a.z + b.z; e2 = e2 > 0.f ? e2 : ALPHA * e2;
      float e3 = a.w + b.w; e3 = e3 > 0.f ? e3 : ALPHA * e3;
      float4 w;
      w.x = __expf(e0 - M[0]); w.y = __expf(e1 - M[1]);
      w.z = __expf(e2 - M[2]); w.w = __expf(e3 - M[3]);
      acc[0] += w.x; acc[1] += w.y; acc[2] += w.z; acc[3] += w.w;
      int pos = atomicAdd(cursor + dd[u], 1);
      sorted_src[pos] = ss[u];
      sorted_w[pos] = w;
    }
  }
  int e = (n4 << 2) + tid;
  if (e < n_edges) {
    int s = srcp[e], d = dstp[e];
    float4 a = ssrc4[s];
    float4 b = sdst4[d];
    float e0 = a.x + b.x; e0 = e0 > 0.f ? e0 : ALPHA * e0;
    float e1 = a.y + b.y; e1 = e1 > 0.f ? e1 : ALPHA * e1;
    float e2 = a.z + b.z; e2 = e2 > 0.f ? e2 : ALPHA * e2;
    float e3 = a.w + b.w; e3 = e3 > 0.f ? e3 : ALPHA * e3;
    float4 w;
    w.x = __expf(e0 - M[0]); w.y = __expf(e1 - M[1]);
    w.z = __expf(e2 - M[2]); w.w = __expf(e3 - M[3]);
    acc[0] += w.x; acc[1] += w.y; acc[2] += w.z; acc[3] += w.w;
    int pos = atomicAdd(cursor + d, 1);
    sorted_src[pos] = s;
    sorted_w[pos] = w;
  }

  __shared__ float red[4][4];
  int lane = threadIdx.x & 63, wv = threadIdx.x >> 6;
#pragma unroll
  for (int c = 0; c < 4; ++c)
#pragma unroll
    for (int o = 32; o; o >>= 1) acc[c] += __shfl_down(acc[c], o);
  if (lane == 0) { red[wv][0] = acc[0]; red[wv][1] = acc[1]; red[wv][2] = acc[2]; red[wv][3] = acc[3]; }
  __syncthreads();
  if (threadIdx.x < 4) {
    float v = red[0][threadIdx.x] + red[1][threadIdx.x] + red[2][threadIdx.x] + red[3][threadIdx.x];
    atomicAdd(gsum + threadIdx.x, v);
  }
}

// ---- two-level exclusive scan of counts ----
__global__ __launch_bounds__(1024) void k_scan1(
    const int* __restrict__ count, int* __restrict__ offs, int* __restrict__ tsum, int n)
{
  __shared__ int sd[1024];
  int t = threadIdx.x;
  int i = blockIdx.x * 1024 + t;
  int c = (i < n) ? count[i] : 0;
  sd[t] = c;
  __syncthreads();
#pragma unroll
  for (int off = 1; off < 1024; off <<= 1) {
    int v = (t >= off) ? sd[t - off] : 0;
    __syncthreads();
    sd[t] += v;
    __syncthreads();
  }
  if (i < n) offs[i] = sd[t] - c;
  if (t == 1023) tsum[blockIdx.x] = sd[1023];
}

__global__ __launch_bounds__(64) void k_scan2(int* __restrict__ tsum, int* __restrict__ tbase, int nb) {
  if (threadIdx.x == 0) {
    int run = 0;
    for (int b = 0; b < nb; ++b) { tbase[b] = run; run += tsum[b]; }
  }
}

__global__ __launch_bounds__(1024) void k_scan3(
    int* __restrict__ offs, const int* __restrict__ tbase,
    int* __restrict__ cursor, int n, int n_edges)
{
  int i = blockIdx.x * 1024 + threadIdx.x;
  if (i < n) {
    int o = offs[i] + tbase[i >> 10];
    offs[i] = o;
    cursor[i] = o;
  }
  if (i == 0) offs[n] = n_edges;
}

// ---- aggregate: one wave per dst, lane = channel; weights precomputed ----
__global__ __launch_bounds__(256) void k_agg(
    const int* __restrict__ offs, const int* __restrict__ sorted_src,
    const float4* __restrict__ sorted_w, const float* __restrict__ Wh,
    const float* __restrict__ gsum, float* __restrict__ out, int n_nodes)
{
  int d = blockIdx.x * 4 + (threadIdx.x >> 6);
  if (d >= n_nodes) return;
  int lane = threadIdx.x & 63;
  int head = lane >> 4;
  int beg = offs[d], end = offs[d + 1];
  float acc = 0.f;
  int j = beg;
  for (; j + 4 <= end; j += 4) {
    int s[4];
    float4 w[4];
#pragma unroll
    for (int u = 0; u < 4; ++u) { s[u] = sorted_src[j + u]; w[u] = sorted_w[j + u]; }
#pragma unroll
    for (int u = 0; u < 4; ++u) {
      float v = Wh[(size_t)s[u] * OUT_C + lane];
      float ww = head == 0 ? w[u].x : head == 1 ? w[u].y : head == 2 ? w[u].z : w[u].w;
      acc += ww * v;
    }
  }
  for (; j < end; ++j) {
    int s = sorted_src[j];
    float4 w4 = sorted_w[j];
    float ww = head == 0 ? w4.x : head == 1 ? w4.y : head == 2 ? w4.z : w4.w;
    acc += ww * Wh[(size_t)s * OUT_C + lane];
  }
  out[(size_t)d * OUT_C + lane] = fmaxf(acc / gsum[head], 0.f);
}

extern "C" void kernel_launch(void* const* d_in, const int* in_sizes, int n_in,
                              void* d_out, int out_size, void* d_ws, size_t ws_size,
                              hipStream_t stream) {
  const int*   ei    = (const int*)d_in[0];
  const float* h     = (const float*)d_in[1];
  const float* W     = (const float*)d_in[2];
  const float* a_src = (const float*)d_in[3];
  const float* a_dst = (const float*)d_in[4];
  float* out = (float*)d_out;

  const int n_edges = in_sizes[0] / 2;
  const int n_nodes = in_sizes[1] / IN_F;
  const int ntiles  = (n_nodes + 1023) / 1024;

  char* ws = (char*)d_ws;
  size_t off = 0;
  auto alloc = [&](size_t bytes) { void* p = ws + off; off = (off + bytes + 15) & ~(size_t)15; return p; };
  float* Wh           = (float*)alloc((size_t)n_nodes * OUT_C * 4);
  float* ssrc         = (float*)alloc((size_t)n_nodes * N_HEADS * 4);
  float* sdst         = (float*)alloc((size_t)n_nodes * N_HEADS * 4);
  unsigned int* gmax_s= (unsigned int*)alloc(N_HEADS * 4);
  unsigned int* gmax_d= (unsigned int*)alloc(N_HEADS * 4);
  float* gsum         = (float*)alloc(N_HEADS * 4);
  int* count          = (int*)alloc((size_t)n_nodes * 4);
  int* offs           = (int*)alloc(((size_t)n_nodes + 1) * 4);
  int* tsum           = (int*)alloc((size_t)ntiles * 4);
  int* tbase          = (int*)alloc((size_t)ntiles * 4);
  int* cursor         = (int*)alloc((size_t)n_nodes * 4);
  float4* sorted_w    = (float4*)alloc((size_t)n_edges * 16);
  int* sorted_src     = (int*)alloc((size_t)n_edges * 4);
  uint4* Wp           = (uint4*)alloc(16 * 64 * 16);   // 16 KB packed W

  hipMemsetAsync(count, 0, (size_t)n_nodes * 4, stream);
  k_init<<<1, 64, 0, stream>>>(gmax_s, gmax_d, gsum);
  k_pack<<<1, 64, 0, stream>>>(W, Wp);
  k_hist<<<1024, 256, 0, stream>>>(ei + n_edges, count, n_edges);
  k_mm<<<(n_nodes + 63) / 64, 256, 0, stream>>>(h, Wp, Wh, n_nodes);
  k_score<<<(n_nodes + 255) / 256, 256, 0, stream>>>(Wh, a_src, a_dst,
      (float4*)ssrc, (float4*)sdst, gmax_s, gmax_d, n_nodes);
  k_scan1<<<ntiles, 1024, 0, stream>>>(count, offs, tsum, n_nodes);
  k_scan2<<<1, 64, 0, stream>>>(tsum, tbase, ntiles);
  k_scan3<<<ntiles, 1024, 0, stream>>>(offs, tbase, cursor, n_nodes, n_edges);
  k_esb<<<1024, 256, 0, stream>>>(ei, (const float4*)ssrc, (const float4*)sdst,
                                  gmax_s, gmax_d, gsum, cursor, sorted_src, sorted_w, n_edges);
  k_agg<<<(n_nodes + 3) / 4, 256, 0, stream>>>(offs, sorted_src, (const float4*)sorted_w,
                                               Wh, gsum, out, n_nodes);
}

// Round 5
// 189.461 us; speedup vs baseline: 19.7822x; 1.1289x over previous
//
#include <hip/hip_runtime.h>
#include <hip/hip_bf16.h>
#include <hip/hip_fp16.h>

#define IN_F 128
#define OUT_F 16
#define N_HEADS 4
#define OUT_C 64   // OUT_F * N_HEADS
#define ALPHA 0.2f

typedef __attribute__((ext_vector_type(8))) short bf16x8;
typedef __attribute__((ext_vector_type(4))) float f32x4;

// ---- order-preserving float<->uint encoding for atomicMax on floats ----
__device__ __forceinline__ unsigned int enc_f(float f) {
  unsigned int u = __float_as_uint(f);
  return (u & 0x80000000u) ? ~u : (u | 0x80000000u);
}
__device__ __forceinline__ float dec_f(unsigned int u) {
  unsigned int b = (u & 0x80000000u) ? (u & 0x7FFFFFFFu) : ~u;
  return __uint_as_float(b);
}

__device__ __forceinline__ ushort f2bf(float f) {
  union { __hip_bfloat16 b; ushort u; } cv;
  cv.b = __float2bfloat16(f);
  return cv.u;
}
__device__ __forceinline__ float bf2f(ushort u) {
  return __uint_as_float(((unsigned int)u) << 16);
}

__global__ __launch_bounds__(64) void k_init(unsigned int* gmax_s, unsigned int* gmax_d,
                                             float* gsum) {
  int t = threadIdx.x;
  if (t < N_HEADS) {
    gmax_s[t] = enc_f(-3.0e38f);
    gmax_d[t] = enc_f(-3.0e38f);
    gsum[t] = 0.f;
  }
}

// ---- pack W (fp32 [128][64]) into B-fragment lane layout, bf16 ----
__global__ __launch_bounds__(64) void k_pack(const float* __restrict__ W,
                                             uint4* __restrict__ Wp) {
  int lane = threadIdx.x;
  int cl = lane & 15, kg = lane >> 4;
#pragma unroll
  for (int ks = 0; ks < 4; ++ks)
#pragma unroll
    for (int ct = 0; ct < 4; ++ct) {
      int c = ct * 16 + cl;
      int k0 = ks * 32 + kg * 8;
      union { ushort u[8]; uint4 q; } P;
#pragma unroll
      for (int j = 0; j < 8; ++j) P.u[j] = f2bf(W[(k0 + j) * OUT_C + c]);
      Wp[(ks * 4 + ct) * 64 + lane] = P.q;
    }
}

// ---- MFMA GEMM: Whb(bf16) = h @ W; fused scores + per-head max epilogue ----
__global__ __launch_bounds__(256) void k_mm(
    const float* __restrict__ h, const uint4* __restrict__ Wp,
    const float* __restrict__ a_src, const float* __restrict__ a_dst,
    ushort* __restrict__ Whb, float4* __restrict__ ssrc4, float4* __restrict__ sdst4,
    unsigned int* __restrict__ gmax_s, unsigned int* __restrict__ gmax_d,
    int n_nodes)
{
  const int wid = threadIdx.x >> 6, lane = threadIdx.x & 63;
  const int r0 = blockIdx.x * 64 + wid * 16;
  const int arow = r0 + (lane & 15);
  const int rclamp = arow < n_nodes ? arow : n_nodes - 1;
  const float* hrow = h + (size_t)rclamp * IN_F + (lane >> 4) * 8;

  f32x4 acc[4];
#pragma unroll
  for (int ct = 0; ct < 4; ++ct) acc[ct] = (f32x4){0.f, 0.f, 0.f, 0.f};

#pragma unroll
  for (int ks = 0; ks < 4; ++ks) {
    float4 a0 = *(const float4*)(hrow + ks * 32);
    float4 a1 = *(const float4*)(hrow + ks * 32 + 4);
    union { ushort u[8]; bf16x8 v; } A;
    A.u[0] = f2bf(a0.x); A.u[1] = f2bf(a0.y); A.u[2] = f2bf(a0.z); A.u[3] = f2bf(a0.w);
    A.u[4] = f2bf(a1.x); A.u[5] = f2bf(a1.y); A.u[6] = f2bf(a1.z); A.u[7] = f2bf(a1.w);
#pragma unroll
    for (int ct = 0; ct < 4; ++ct) {
      union { uint4 q; bf16x8 v; } B;
      B.q = Wp[(ks * 4 + ct) * 64 + lane];
      acc[ct] = __builtin_amdgcn_mfma_f32_16x16x32_bf16(A.v, B.v, acc[ct], 0, 0, 0);
    }
  }

  // epilogue: C layout col = ct*16 + (lane&15), row = r0 + (lane>>4)*4 + j
  const int cl = lane & 15, g = lane >> 4;
  float as_[4], ad_[4];
#pragma unroll
  for (int ct = 0; ct < 4; ++ct) { as_[ct] = a_src[ct * 16 + cl]; ad_[ct] = a_dst[ct * 16 + cl]; }

  float ms[4], md[4];
#pragma unroll
  for (int ct = 0; ct < 4; ++ct) { ms[ct] = -3.0e38f; md[ct] = -3.0e38f; }

#pragma unroll
  for (int j = 0; j < 4; ++j) {
    int r = r0 + g * 4 + j;
    bool rv = r < n_nodes;
    float ps[4], pd[4];
#pragma unroll
    for (int ct = 0; ct < 4; ++ct) {
      float v = acc[ct][j];
      if (rv) Whb[(size_t)r * OUT_C + ct * 16 + cl] = f2bf(v);
      ps[ct] = v * as_[ct];
      pd[ct] = v * ad_[ct];
    }
    // reduce over the 16 lanes of the group (per-head partial sums)
#pragma unroll
    for (int o = 1; o < 16; o <<= 1) {
#pragma unroll
      for (int ct = 0; ct < 4; ++ct) {
        ps[ct] += __shfl_xor(ps[ct], o);
        pd[ct] += __shfl_xor(pd[ct], o);
      }
    }
    if (rv && cl == 0) {
      ssrc4[r] = make_float4(ps[0], ps[1], ps[2], ps[3]);
      sdst4[r] = make_float4(pd[0], pd[1], pd[2], pd[3]);
    }
    if (rv) {
#pragma unroll
      for (int ct = 0; ct < 4; ++ct) {
        ms[ct] = fmaxf(ms[ct], ps[ct]);
        md[ct] = fmaxf(md[ct], pd[ct]);
      }
    }
  }
  // wave max across groups, then block-level LDS reduce, one atomic set per block
#pragma unroll
  for (int o = 16; o < 64; o <<= 1) {
#pragma unroll
    for (int ct = 0; ct < 4; ++ct) {
      ms[ct] = fmaxf(ms[ct], __shfl_xor(ms[ct], o));
      md[ct] = fmaxf(md[ct], __shfl_xor(md[ct], o));
    }
  }
  __shared__ float wmS[4][4], wmD[4][4];
  if (lane == 0) {
#pragma unroll
    for (int ct = 0; ct < 4; ++ct) { wmS[wid][ct] = ms[ct]; wmD[wid][ct] = md[ct]; }
  }
  __syncthreads();
  if (threadIdx.x < N_HEADS) {
    int t = threadIdx.x;
    float vs = fmaxf(fmaxf(wmS[0][t], wmS[1][t]), fmaxf(wmS[2][t], wmS[3][t]));
    float vd = fmaxf(fmaxf(wmD[0][t], wmD[1][t]), fmaxf(wmD[2][t], wmD[3][t]));
    atomicMax(gmax_s + t, enc_f(vs));
    atomicMax(gmax_d + t, enc_f(vd));
  }
}

// ---- dst-degree histogram (dst column only: 4 MB) ----
__global__ __launch_bounds__(256) void k_hist(
    const int* __restrict__ dst, int* __restrict__ count, int n_edges)
{
  int n4 = n_edges >> 2;
  int stride = gridDim.x * blockDim.x;
  for (int i = blockIdx.x * blockDim.x + threadIdx.x; i < n4; i += stride) {
    int4 d = ((const int4*)dst)[i];
    atomicAdd(count + d.x, 1);
    atomicAdd(count + d.y, 1);
    atomicAdd(count + d.z, 1);
    atomicAdd(count + d.w, 1);
  }
  int t = blockIdx.x * blockDim.x + threadIdx.x;
  int e = (n4 << 2) + t;
  if (e < n_edges) atomicAdd(count + dst[e], 1);
}

// ---- fused: per-edge fp16 weight numerators + gsum + bucket-by-dst ----
__global__ __launch_bounds__(256) void k_esb(
    const int* __restrict__ ei, const float4* __restrict__ ssrc4,
    const float4* __restrict__ sdst4, const unsigned int* __restrict__ gmax_s,
    const unsigned int* __restrict__ gmax_d, float* __restrict__ gsum,
    int* __restrict__ cursor, int* __restrict__ sorted_src,
    uint2* __restrict__ sorted_wq, int n_edges)
{
  float M[4];
#pragma unroll
  for (int c = 0; c < 4; ++c) {
    float m = dec_f(gmax_s[c]) + dec_f(gmax_d[c]);   // upper bound on edge max
    M[c] = m > 0.f ? m : ALPHA * m;                  // LReLU monotone
  }
  float acc[4] = {0.f, 0.f, 0.f, 0.f};
  const int* srcp = ei;
  const int* dstp = ei + n_edges;
  int n4 = n_edges >> 2;
  int stride = gridDim.x * blockDim.x;
  int tid = blockIdx.x * blockDim.x + threadIdx.x;

  for (int i = tid; i < n4; i += stride) {
    int4 sv = ((const int4*)srcp)[i];
    int4 dv = ((const int4*)dstp)[i];
    int ss[4] = {sv.x, sv.y, sv.z, sv.w};
    int dd[4] = {dv.x, dv.y, dv.z, dv.w};
#pragma unroll
    for (int u = 0; u < 4; ++u) {
      float4 a = ssrc4[ss[u]];
      float4 b = sdst4[dd[u]];
      float e0 = a.x + b.x; e0 = e0 > 0.f ? e0 : ALPHA * e0;
      float e1 = a.y + b.y; e1 = e1 > 0.f ? e1 : ALPHA * e1;
      float e2 = a.z + b.z; e2 = e2 > 0.f ? e2 : ALPHA * e2;
      float e3 = a.w + b.w; e3 = e3 > 0.f ? e3 : ALPHA * e3;
      float w0 = __expf(e0 - M[0]), w1 = __expf(e1 - M[1]);
      float w2 = __expf(e2 - M[2]), w3 = __expf(e3 - M[3]);
      acc[0] += w0; acc[1] += w1; acc[2] += w2; acc[3] += w3;
      unsigned int lo = (unsigned int)__half_as_ushort(__float2half(w0)) |
                        ((unsigned int)__half_as_ushort(__float2half(w1)) << 16);
      unsigned int hi = (unsigned int)__half_as_ushort(__float2half(w2)) |
                        ((unsigned int)__half_as_ushort(__float2half(w3)) << 16);
      int pos = atomicAdd(cursor + dd[u], 1);
      sorted_src[pos] = ss[u];
      sorted_wq[pos] = make_uint2(lo, hi);
    }
  }
  int e = (n4 << 2) + tid;
  if (e < n_edges) {
    int s = srcp[e], d = dstp[e];
    float4 a = ssrc4[s];
    float4 b = sdst4[d];
    float e0 = a.x + b.x; e0 = e0 > 0.f ? e0 : ALPHA * e0;
    float e1 = a.y + b.y; e1 = e1 > 0.f ? e1 : ALPHA * e1;
    float e2 = a.z + b.z; e2 = e2 > 0.f ? e2 : ALPHA * e2;
    float e3 = a.w + b.w; e3 = e3 > 0.f ? e3 : ALPHA * e3;
    float w0 = __expf(e0 - M[0]), w1 = __expf(e1 - M[1]);
    float w2 = __expf(e2 - M[2]), w3 = __expf(e3 - M[3]);
    acc[0] += w0; acc[1] += w1; acc[2] += w2; acc[3] += w3;
    unsigned int lo = (unsigned int)__half_as_ushort(__float2half(w0)) |
                      ((unsigned int)__half_as_ushort(__float2half(w1)) << 16);
    unsigned int hi = (unsigned int)__half_as_ushort(__float2half(w2)) |
                      ((unsigned int)__half_as_ushort(__float2half(w3)) << 16);
    int pos = atomicAdd(cursor + d, 1);
    sorted_src[pos] = s;
    sorted_wq[pos] = make_uint2(lo, hi);
  }

  __shared__ float red[4][4];
  int lane = threadIdx.x & 63, wv = threadIdx.x >> 6;
#pragma unroll
  for (int c = 0; c < 4; ++c)
#pragma unroll
    for (int o = 32; o; o >>= 1) acc[c] += __shfl_down(acc[c], o);
  if (lane == 0) { red[wv][0] = acc[0]; red[wv][1] = acc[1]; red[wv][2] = acc[2]; red[wv][3] = acc[3]; }
  __syncthreads();
  if (threadIdx.x < 4) {
    float v = red[0][threadIdx.x] + red[1][threadIdx.x] + red[2][threadIdx.x] + red[3][threadIdx.x];
    atomicAdd(gsum + threadIdx.x, v);
  }
}

// ---- two-level exclusive scan of counts ----
__global__ __launch_bounds__(1024) void k_scan1(
    const int* __restrict__ count, int* __restrict__ offs, int* __restrict__ tsum, int n)
{
  __shared__ int sd[1024];
  int t = threadIdx.x;
  int i = blockIdx.x * 1024 + t;
  int c = (i < n) ? count[i] : 0;
  sd[t] = c;
  __syncthreads();
#pragma unroll
  for (int off = 1; off < 1024; off <<= 1) {
    int v = (t >= off) ? sd[t - off] : 0;
    __syncthreads();
    sd[t] += v;
    __syncthreads();
  }
  if (i < n) offs[i] = sd[t] - c;
  if (t == 1023) tsum[blockIdx.x] = sd[1023];
}

__global__ __launch_bounds__(64) void k_scan2(int* __restrict__ tsum, int* __restrict__ tbase, int nb) {
  if (threadIdx.x == 0) {
    int run = 0;
    for (int b = 0; b < nb; ++b) { tbase[b] = run; run += tsum[b]; }
  }
}

__global__ __launch_bounds__(1024) void k_scan3(
    int* __restrict__ offs, const int* __restrict__ tbase,
    int* __restrict__ cursor, int n, int n_edges)
{
  int i = blockIdx.x * 1024 + threadIdx.x;
  if (i < n) {
    int o = offs[i] + tbase[i >> 10];
    offs[i] = o;
    cursor[i] = o;
  }
  if (i == 0) offs[n] = n_edges;
}

// ---- aggregate: one wave per dst, lane = channel; bf16 Wh, fp16 weights ----
__global__ __launch_bounds__(256) void k_agg(
    const int* __restrict__ offs, const int* __restrict__ sorted_src,
    const __half* __restrict__ sorted_wh, const ushort* __restrict__ Whb,
    const float* __restrict__ gsum, float* __restrict__ out, int n_nodes)
{
  int d = blockIdx.x * 4 + (threadIdx.x >> 6);
  if (d >= n_nodes) return;
  int lane = threadIdx.x & 63;
  int head = lane >> 4;
  int beg = offs[d], end = offs[d + 1];
  float acc = 0.f;
  int j = beg;
  for (; j + 4 <= end; j += 4) {
    int s[4];
    float wv[4];
#pragma unroll
    for (int u = 0; u < 4; ++u) {
      s[u] = sorted_src[j + u];
      wv[u] = __half2float(sorted_wh[(size_t)(j + u) * 4 + head]);
    }
#pragma unroll
    for (int u = 0; u < 4; ++u) {
      float v = bf2f(Whb[(size_t)s[u] * OUT_C + lane]);
      acc += wv[u] * v;
    }
  }
  for (; j < end; ++j) {
    int s = sorted_src[j];
    float w = __half2float(sorted_wh[(size_t)j * 4 + head]);
    acc += w * bf2f(Whb[(size_t)s * OUT_C + lane]);
  }
  out[(size_t)d * OUT_C + lane] = fmaxf(acc / gsum[head], 0.f);
}

extern "C" void kernel_launch(void* const* d_in, const int* in_sizes, int n_in,
                              void* d_out, int out_size, void* d_ws, size_t ws_size,
                              hipStream_t stream) {
  const int*   ei    = (const int*)d_in[0];
  const float* h     = (const float*)d_in[1];
  const float* W     = (const float*)d_in[2];
  const float* a_src = (const float*)d_in[3];
  const float* a_dst = (const float*)d_in[4];
  float* out = (float*)d_out;

  const int n_edges = in_sizes[0] / 2;
  const int n_nodes = in_sizes[1] / IN_F;
  const int ntiles  = (n_nodes + 1023) / 1024;

  char* ws = (char*)d_ws;
  size_t off = 0;
  auto alloc = [&](size_t bytes) { void* p = ws + off; off = (off + bytes + 15) & ~(size_t)15; return p; };
  ushort* Whb         = (ushort*)alloc((size_t)n_nodes * OUT_C * 2);
  float* ssrc         = (float*)alloc((size_t)n_nodes * N_HEADS * 4);
  float* sdst         = (float*)alloc((size_t)n_nodes * N_HEADS * 4);
  unsigned int* gmax_s= (unsigned int*)alloc(N_HEADS * 4);
  unsigned int* gmax_d= (unsigned int*)alloc(N_HEADS * 4);
  float* gsum         = (float*)alloc(N_HEADS * 4);
  int* count          = (int*)alloc((size_t)n_nodes * 4);
  int* offs           = (int*)alloc(((size_t)n_nodes + 1) * 4);
  int* tsum           = (int*)alloc((size_t)ntiles * 4);
  int* tbase          = (int*)alloc((size_t)ntiles * 4);
  int* cursor         = (int*)alloc((size_t)n_nodes * 4);
  uint2* sorted_wq    = (uint2*)alloc((size_t)n_edges * 8);
  int* sorted_src     = (int*)alloc((size_t)n_edges * 4);
  uint4* Wp           = (uint4*)alloc(16 * 64 * 16);   // 16 KB packed W

  hipMemsetAsync(count, 0, (size_t)n_nodes * 4, stream);
  k_init<<<1, 64, 0, stream>>>(gmax_s, gmax_d, gsum);
  k_pack<<<1, 64, 0, stream>>>(W, Wp);
  k_hist<<<1024, 256, 0, stream>>>(ei + n_edges, count, n_edges);
  k_mm<<<(n_nodes + 63) / 64, 256, 0, stream>>>(h, Wp, a_src, a_dst, Whb,
      (float4*)ssrc, (float4*)sdst, gmax_s, gmax_d, n_nodes);
  k_scan1<<<ntiles, 1024, 0, stream>>>(count, offs, tsum, n_nodes);
  k_scan2<<<1, 64, 0, stream>>>(tsum, tbase, ntiles);
  k_scan3<<<ntiles, 1024, 0, stream>>>(offs, tbase, cursor, n_nodes, n_edges);
  k_esb<<<1024, 256, 0, stream>>>(ei, (const float4*)ssrc, (const float4*)sdst,
                                  gmax_s, gmax_d, gsum, cursor, sorted_src, sorted_wq, n_edges);
  k_agg<<<(n_nodes + 3) / 4, 256, 0, stream>>>(offs, sorted_src,
      (const __half*)sorted_wq, Whb, gsum, out, n_nodes);
}